// Round 16
// baseline (66.937 us; speedup 1.0000x reference)
//
#include <hip/hip_runtime.h>

// Problem constants
#define BB 64
#define NN 512
#define MM 30
#define E2 4
#define NE 32
#define NE4 8
#define NF 64
#define BN_TOTAL (BB * NN)   // 32768
#define TP2 40                // padded row (u16) of the bf16 h1 tile: stride 80 B
#define HP 65                 // padded row (floats) of HT tiles in k_fit

typedef __attribute__((ext_vector_type(8))) short bf16x8;
typedef __attribute__((ext_vector_type(4))) float vf4;

// Fast activations: raw v_rcp_f32 (~1 ulp) instead of the IEEE div sequence.
__device__ __forceinline__ float frcp(float x) { return __builtin_amdgcn_rcpf(x); }
__device__ __forceinline__ float fsig(float x)  { return frcp(1.0f + __expf(-x)); }
__device__ __forceinline__ float ftanh(float x) { return 1.0f - 2.0f * frcp(1.0f + __expf(2.0f * x)); }

union fragu { unsigned u[4]; bf16x8 v; };

__device__ __forceinline__ unsigned cvt_pk_bf16(float a, float b) {
    unsigned r;
    asm("v_cvt_pk_bf16_f32 %0, %1, %2" : "=v"(r) : "v"(a), "v"(b));
    return r;
}
__device__ __forceinline__ float lo16f(unsigned u) { return __uint_as_float(u << 16); }
__device__ __forceinline__ float hi16f(unsigned u) { return __uint_as_float(u & 0xFFFF0000u); }

// Split 8 fp32 (a.xyzw, b.xyzw) into hi/lo bf16 fragments (RNE via v_cvt_pk_bf16_f32).
__device__ __forceinline__ void split8v(vf4 a, vf4 b, bf16x8& hi, bf16x8& lo) {
    fragu H, L;
    H.u[0] = cvt_pk_bf16(a.x, a.y);
    H.u[1] = cvt_pk_bf16(a.z, a.w);
    H.u[2] = cvt_pk_bf16(b.x, b.y);
    H.u[3] = cvt_pk_bf16(b.z, b.w);
    L.u[0] = cvt_pk_bf16(a.x - lo16f(H.u[0]), a.y - hi16f(H.u[0]));
    L.u[1] = cvt_pk_bf16(a.z - lo16f(H.u[1]), a.w - hi16f(H.u[1]));
    L.u[2] = cvt_pk_bf16(b.x - lo16f(H.u[2]), b.y - hi16f(H.u[2]));
    L.u[3] = cvt_pk_bf16(b.z - lo16f(H.u[3]), b.w - hi16f(H.u[3]));
    hi = H.v; lo = L.v;
}

// 3-term split-precision MFMA: C += A*B with A=Ah+Al, B=Bh+Bl (lolo dropped).
__device__ __forceinline__ vf4 mm3(bf16x8 ah, bf16x8 al, bf16x8 bh, bf16x8 bl, vf4 c) {
    c = __builtin_amdgcn_mfma_f32_16x16x32_bf16(ah, bh, c, 0, 0, 0);
    c = __builtin_amdgcn_mfma_f32_16x16x32_bf16(ah, bl, c, 0, 0, 0);
    c = __builtin_amdgcn_mfma_f32_16x16x32_bf16(al, bh, c, 0, 0, 0);
    return c;
}

// 2-term: A single bf16, B split (used for layer 2 where A=bf16(h1)).
__device__ __forceinline__ vf4 mm2(bf16x8 a, bf16x8 bh, bf16x8 bl, vf4 c) {
    c = __builtin_amdgcn_mfma_f32_16x16x32_bf16(a, bh, c, 0, 0, 0);
    c = __builtin_amdgcn_mfma_f32_16x16x32_bf16(a, bl, c, 0, 0, 0);
    return c;
}

__device__ __forceinline__ vf4 ld4(const float* p) { return *(const vf4*)p; }

// ---------------------------------------------------------------------------
// K0: one-time weight-fragment precompute.
//  blocks 0..7 : Wf0 B-frags (fit layer 0), 32 combos (k<8 x nt<4), 64 KB
//  blocks 8..9 : Wf1 B-frags (fit layer 1),  8 combos (ktile<2 x nt<4), 16 KB
//  blocks 10..11: Wf2 B-frags (fit layer 2),  8 combos, 16 KB
//  block 12   : We1/We2 frags for k_emb (8 KB)
// ---------------------------------------------------------------------------
__global__ __launch_bounds__(256) void k_prep(
    const float* __restrict__ We1, const float* __restrict__ We2,
    const float* __restrict__ Wf0, const float* __restrict__ Wf1,
    const float* __restrict__ Wf2,
    bf16x8* __restrict__ fragsE, bf16x8* __restrict__ fragsF,
    bf16x8* __restrict__ fragsG1, bf16x8* __restrict__ fragsG2)
{
    const int tid  = threadIdx.x;
    const int l    = tid & 63;
    const int row0 = l & 15;
    const int grp  = l >> 4;
    const int bid  = blockIdx.x;

    if (bid < 8) {
        const int combo = bid * 4 + (tid >> 6);          // 0..31
        const int k  = combo >> 2;
        const int nt = combo & 3;
        const float* wp = Wf0 + (size_t)(k * 32 + grp * 8) * NF + nt * 16 + row0;
        vf4 x0 = { wp[0],      wp[NF],     wp[2 * NF], wp[3 * NF] };
        vf4 x1 = { wp[4 * NF], wp[5 * NF], wp[6 * NF], wp[7 * NF] };
        bf16x8 h, lo;
        split8v(x0, x1, h, lo);
        fragsF[(combo * 2 + 0) * 64 + l] = h;
        fragsF[(combo * 2 + 1) * 64 + l] = lo;
    } else if (bid < 12) {
        const int layer = (bid - 8) >> 1;                // 0 -> Wf1, 1 -> Wf2
        const int combo = ((bid - 8) & 1) * 4 + (tid >> 6);   // 0..7
        const int ktile = combo >> 2;
        const int nt    = combo & 3;
        const float* W  = layer ? Wf2 : Wf1;
        bf16x8* out     = layer ? fragsG2 : fragsG1;
        const float* wp = W + (size_t)(ktile * 32 + grp * 8) * NF + nt * 16 + row0;
        vf4 x0 = { wp[0],      wp[NF],     wp[2 * NF], wp[3 * NF] };
        vf4 x1 = { wp[4 * NF], wp[5 * NF], wp[6 * NF], wp[7 * NF] };
        bf16x8 h, lo;
        split8v(x0, x1, h, lo);
        out[(combo * 2 + 0) * 64 + l] = h;
        out[(combo * 2 + 1) * 64 + l] = lo;
    } else if (tid < 64) {
#pragma unroll
        for (int nt = 0; nt < 2; ++nt) {
            const float* wp = We1 + (size_t)(grp * 8) * NE + nt * 16 + row0;
            vf4 x0 = { wp[0],      wp[NE],     wp[2 * NE], wp[3 * NE] };
            vf4 x1 = { wp[4 * NE], wp[5 * NE], wp[6 * NE], wp[7 * NE] };
            bf16x8 h, lo;
            split8v(x0, x1, h, lo);
            fragsE[(0 + nt) * 64 + l] = h;
            fragsE[(2 + nt) * 64 + l] = lo;
            const float* wq = We2 + (size_t)(grp * 8) * NE + nt * 16 + row0;
            vf4 y0 = { wq[0],      wq[NE],     wq[2 * NE], wq[3 * NE] };
            vf4 y1 = { wq[4 * NE], wq[5 * NE], wq[6 * NE], wq[7 * NE] };
            split8v(y0, y1, h, lo);
            fragsE[(4 + nt) * 64 + l] = h;
            fragsE[(6 + nt) * 64 + l] = lo;
        }
    }
}

// ---------------------------------------------------------------------------
// K1 v7 (MFMA): one wave per (b,n) pair, 2-wave blocks. (round-13 state)
// h1 transpose tile stored as SINGLE bf16 (RNE) u16 — the b128 read IS the
// layer-2 A-fragment. Layer-1 path fully split (3-term); weights split.
// Verified layouts (absmax 0.0): A row=lane&15, k=(lane>>4)*8+e;
// B k=(lane>>4)*8+e, col=lane&15; C col=lane&15, row=(lane>>4)*4+reg.
// Identity A[k][l]=Bm[l][k] => D = Bm^T Bm. Pad rows 30,31 have R=0.
// ---------------------------------------------------------------------------
__global__ __launch_bounds__(128) void k_emb_mfma(
    const float* __restrict__ Sg, const float* __restrict__ R,
    const float* __restrict__ We0, const float* __restrict__ be0,
    const float* __restrict__ be1, const float* __restrict__ be2,
    const bf16x8* __restrict__ frags,
    float* __restrict__ Dout)
{
    __shared__ unsigned short T16[2][32 * TP2];   // bf16 h1 tile, 2560 B/wave
    __shared__ vf4 Rl[2][32];                     // R rows (30,31 zeroed)

    const int tid  = threadIdx.x;
    const int w    = tid >> 6;
    const int l    = tid & 63;
    const int row0 = l & 15;
    const int grp  = l >> 4;
    const int pair = blockIdx.x * 2 + w;

    // ---- stage R (rows 30,31 = 0) ----
    if (l < 32) {
        vf4 rv = 0.f;
        if (l < MM) rv = ld4(R + ((size_t)pair * MM + l) * 4);
        Rl[w][l] = rv;
    }

    // ---- precomputed B-fragments: 8 x b128 ----
    bf16x8 B1h[2], B1l[2], B2h[2], B2l[2];
#pragma unroll
    for (int nt = 0; nt < 2; ++nt) {
        B1h[nt] = frags[(0 + nt) * 64 + l];
        B1l[nt] = frags[(2 + nt) * 64 + l];
        B2h[nt] = frags[(4 + nt) * 64 + l];
        B2l[nt] = frags[(6 + nt) * 64 + l];
    }

    // ---- layer-0 weights (lane-indexed, L1-resident) ----
    vf4 w0[4][2];
#pragma unroll
    for (int i = 0; i < 4; ++i) {
        w0[i][0] = ld4(We0 + i * NE + grp * 8);
        w0[i][1] = ld4(We0 + i * NE + grp * 8 + 4);
    }
    const vf4 b0a = ld4(be0 + grp * 8);
    const vf4 b0b = ld4(be0 + grp * 8 + 4);
    const float bias1[2] = { be1[row0], be1[row0 + 16] };
    const float bias2[2] = { be2[row0], be2[row0 + 16] };

    // ---- layer 0: 4 -> 32, sigmoid; build A-frags for layer 1 ----
    bf16x8 Ah[2], Al[2];
#pragma unroll
    for (int t = 0; t < 2; ++t) {
        const int p = 16 * t + row0;
        vf4 s = 0.f;
        if (p < MM) s = ld4(Sg + ((size_t)pair * MM + p) * 4);
        vf4 acc0 = b0a + s.x * w0[0][0] + s.y * w0[1][0] + s.z * w0[2][0] + s.w * w0[3][0];
        vf4 acc1 = b0b + s.x * w0[0][1] + s.y * w0[1][1] + s.z * w0[2][1] + s.w * w0[3][1];
#pragma unroll
        for (int e = 0; e < 4; ++e) { acc0[e] = fsig(acc0[e]); acc1[e] = fsig(acc1[e]); }
        split8v(acc0, acc1, Ah[t], Al[t]);
    }

    // ---- layer 1 MFMA (3-term, bias in accumulator init) ----
    vf4 H1[2][2];
#pragma unroll
    for (int t = 0; t < 2; ++t)
#pragma unroll
        for (int nt = 0; nt < 2; ++nt) {
            vf4 c = bias1[nt];
            H1[t][nt] = mm3(Ah[t], Al[t], B1h[nt], B1l[nt], c);
        }

    // ---- tanh -> bf16 -> transposed u16 tile ----
#pragma unroll
    for (int t = 0; t < 2; ++t)
#pragma unroll
        for (int nt = 0; nt < 2; ++nt)
#pragma unroll
            for (int e = 0; e < 4; ++e) {
                const float v = ftanh(H1[t][nt][e]);
                T16[w][(grp * 4 + e + 16 * t) * TP2 + row0 + 16 * nt] =
                    (unsigned short)(cvt_pk_bf16(v, v) & 0xFFFFu);
            }

    // ---- layer-2 A-frags: direct b128 read (16B-aligned: 80*(16t+row0)+16g) ----
    bf16x8 A2[2];
#pragma unroll
    for (int t = 0; t < 2; ++t)
        A2[t] = *(const bf16x8*)&T16[w][(16 * t + row0) * TP2 + grp * 8];

    // ---- layer 2 MFMA (2-term): G = h1' @ We2 + be2 ----
    vf4 G[2][2];
#pragma unroll
    for (int t = 0; t < 2; ++t)
#pragma unroll
        for (int nt = 0; nt < 2; ++nt) {
            vf4 c = bias2[nt];
            G[t][nt] = mm2(A2[t], B2h[nt], B2l[nt], c);
        }

    // ---- Bm[l][col] = sum_m R[m][l]*G[m][col] ----
    float bm[4][2] = {{0.f, 0.f}, {0.f, 0.f}, {0.f, 0.f}, {0.f, 0.f}};
#pragma unroll
    for (int t = 0; t < 2; ++t)
#pragma unroll
        for (int e = 0; e < 4; ++e) {
            const int rrow = grp * 4 + e + 16 * t;
            const vf4 r4 = Rl[w][rrow];
#pragma unroll
            for (int nt = 0; nt < 2; ++nt) {
                const float gv = G[t][nt][e];
                bm[0][nt] += r4.x * gv;
                bm[1][nt] += r4.y * gv;
                bm[2][nt] += r4.z * gv;
                bm[3][nt] += r4.w * gv;
            }
        }
    float bmv[4][2];
#pragma unroll
    for (int li = 0; li < 4; ++li)
#pragma unroll
        for (int nt = 0; nt < 2; ++nt) {
            float v = bm[li][nt];
            v += __shfl_xor(v, 16);
            v += __shfl_xor(v, 32);
            bmv[li][nt] = v;
        }

    // ---- D[k][n] = sum_l Bm[l][k]*Bm[l][n]; lane: k=2grp+kk, n=row0+16nt ----
    float d[2][2] = {{0.f, 0.f}, {0.f, 0.f}};
#pragma unroll
    for (int kk = 0; kk < 2; ++kk) {
        const int src = grp * 2 + kk;
#pragma unroll
        for (int li = 0; li < 4; ++li) {
            const float a = __shfl(bmv[li][0], src);
#pragma unroll
            for (int nt = 0; nt < 2; ++nt) d[kk][nt] += a * bmv[li][nt];
        }
    }

    float* __restrict__ dp = Dout + (size_t)pair * 256;
#pragma unroll
    for (int kk = 0; kk < 2; ++kk)
#pragma unroll
        for (int nt = 0; nt < 2; ++nt)
            dp[(grp * 2 + kk) * NE + nt * 16 + row0] = d[kk][nt];
}

// ---------------------------------------------------------------------------
// K2 v5: fit MLP — all layers MFMA (round-13 state: f32 HT tiles, 3-term).
// Rows stay with the wave -> all tile traffic same-wave, no mid-kernel syncs.
// ---------------------------------------------------------------------------
__global__ __launch_bounds__(256) void k_fit4(
    const float* __restrict__ D, const bf16x8* __restrict__ fragsF,
    const bf16x8* __restrict__ fragsG1, const bf16x8* __restrict__ fragsG2,
    const float* __restrict__ bf0, const float* __restrict__ bf1,
    const float* __restrict__ bf2,
    const float* __restrict__ Wf3, const float* __restrict__ bf3,
    float* __restrict__ Q)
{
    __shared__ float HT0[64 * HP];   // 16.25 KB, [feat][row]
    __shared__ float HT1[64 * HP];   // 16.25 KB, [feat][row]
    __shared__ float Qp[64];

    const int tid  = threadIdx.x;
    const int wv   = tid >> 6;
    const int l    = tid & 63;
    const int row0 = l & 15;
    const int grp  = l >> 4;

    // ---------------- layer 0 (MFMA): D[256] -> 64, tanh ----------------
    {
        const float* __restrict__ drow =
            D + (size_t)(blockIdx.x * 64 + wv * 16 + row0) * 256;

        vf4 c[4];
#pragma unroll
        for (int nt = 0; nt < 4; ++nt) c[nt] = bf0[nt * 16 + row0];

#pragma unroll
        for (int k = 0; k < 8; ++k) {
            vf4 x0 = ld4(drow + k * 32 + grp * 8);
            vf4 x1 = ld4(drow + k * 32 + grp * 8 + 4);
            bf16x8 ah, al;
            split8v(x0, x1, ah, al);
#pragma unroll
            for (int nt = 0; nt < 4; ++nt) {
                const int combo = k * 4 + nt;
                c[nt] = mm3(ah, al, fragsF[(combo * 2 + 0) * 64 + l],
                                    fragsF[(combo * 2 + 1) * 64 + l], c[nt]);
            }
        }
#pragma unroll
        for (int nt = 0; nt < 4; ++nt)
#pragma unroll
            for (int e = 0; e < 4; ++e)
                HT0[(nt * 16 + row0) * HP + wv * 16 + grp * 4 + e] = ftanh(c[nt][e]);
    }

    // ---------------- layer 1 (MFMA): 64 -> 64, sigmoid ----------------
    {
        vf4 c[4];
#pragma unroll
        for (int nt = 0; nt < 4; ++nt) c[nt] = bf1[nt * 16 + row0];
#pragma unroll
        for (int ktile = 0; ktile < 2; ++ktile) {
            vf4 x0, x1;
#pragma unroll
            for (int e = 0; e < 4; ++e) {
                x0[e] = HT0[(ktile * 32 + grp * 8 + e) * HP + wv * 16 + row0];
                x1[e] = HT0[(ktile * 32 + grp * 8 + 4 + e) * HP + wv * 16 + row0];
            }
            bf16x8 ah, al;
            split8v(x0, x1, ah, al);
#pragma unroll
            for (int nt = 0; nt < 4; ++nt) {
                const int combo = ktile * 4 + nt;
                c[nt] = mm3(ah, al, fragsG1[(combo * 2 + 0) * 64 + l],
                                    fragsG1[(combo * 2 + 1) * 64 + l], c[nt]);
            }
        }
#pragma unroll
        for (int nt = 0; nt < 4; ++nt)
#pragma unroll
            for (int e = 0; e < 4; ++e)
                HT1[(nt * 16 + row0) * HP + wv * 16 + grp * 4 + e] = fsig(c[nt][e]);
    }

    // ---------------- layer 2 (MFMA): 64 -> 64 (tanh in L3) -------------
    vf4 c2[4];
    {
#pragma unroll
        for (int nt = 0; nt < 4; ++nt) c2[nt] = bf2[nt * 16 + row0];
#pragma unroll
        for (int ktile = 0; ktile < 2; ++ktile) {
            vf4 x0, x1;
#pragma unroll
            for (int e = 0; e < 4; ++e) {
                x0[e] = HT1[(ktile * 32 + grp * 8 + e) * HP + wv * 16 + row0];
                x1[e] = HT1[(ktile * 32 + grp * 8 + 4 + e) * HP + wv * 16 + row0];
            }
            bf16x8 ah, al;
            split8v(x0, x1, ah, al);
#pragma unroll
            for (int nt = 0; nt < 4; ++nt) {
                const int combo = ktile * 4 + nt;
                c2[nt] = mm3(ah, al, fragsG2[(combo * 2 + 0) * 64 + l],
                                     fragsG2[(combo * 2 + 1) * 64 + l], c2[nt]);
            }
        }
    }

    // ---------------- layer 3: tanh + dot with Wf3, reduce over row0 ----
    {
        float p[4] = {0.f, 0.f, 0.f, 0.f};   // rows wv*16 + grp*4 + e
#pragma unroll
        for (int nt = 0; nt < 4; ++nt) {
            const float w3 = Wf3[nt * 16 + row0];
#pragma unroll
            for (int e = 0; e < 4; ++e) p[e] += ftanh(c2[nt][e]) * w3;
        }
#pragma unroll
        for (int e = 0; e < 4; ++e) {
            float v = p[e];
            v += __shfl_xor(v, 1);
            v += __shfl_xor(v, 2);
            v += __shfl_xor(v, 4);
            v += __shfl_xor(v, 8);
            if (row0 == 0) Qp[wv * 16 + grp * 4 + e] = v;
        }
    }
    __syncthreads();

    if (tid < 64)
        Q[(size_t)blockIdx.x * 64 + tid] = bf3[0] + Qp[tid];
}

// ---------------------------------------------------------------------------
// K3: deterministic mean over N per batch element.
// ---------------------------------------------------------------------------
__global__ __launch_bounds__(256) void k_mean(const float* __restrict__ Q,
                                              float* __restrict__ out)
{
    __shared__ float s[256];
    const int b = blockIdx.x;
    const int t = threadIdx.x;
    float v = Q[b * NN + t] + Q[b * NN + 256 + t];
    s[t] = v;
    __syncthreads();
#pragma unroll
    for (int off = 128; off > 0; off >>= 1) {
        if (t < off) s[t] += s[t + off];
        __syncthreads();
    }
    if (t == 0) out[b] = s[0] * (1.0f / (float)NN);
}

// ---------------------------------------------------------------------------
extern "C" void kernel_launch(void* const* d_in, const int* in_sizes, int n_in,
                              void* d_out, int out_size, void* d_ws, size_t ws_size,
                              hipStream_t stream)
{
    const float* Sg  = (const float*)d_in[0];
    const float* R   = (const float*)d_in[1];
    const float* We0 = (const float*)d_in[2];
    const float* be0 = (const float*)d_in[3];
    const float* We1 = (const float*)d_in[4];
    const float* be1 = (const float*)d_in[5];
    const float* We2 = (const float*)d_in[6];
    const float* be2 = (const float*)d_in[7];
    const float* Wf0 = (const float*)d_in[8];
    const float* bf0 = (const float*)d_in[9];
    const float* Wf1 = (const float*)d_in[10];
    const float* bf1 = (const float*)d_in[11];
    const float* Wf2 = (const float*)d_in[12];
    const float* bf2 = (const float*)d_in[13];
    const float* Wf3 = (const float*)d_in[14];
    const float* bf3 = (const float*)d_in[15];

    char* ws = (char*)d_ws;
    float*  Dm      = (float*)ws;                                  // 33.55 MB
    float*  Q       = (float*)(ws + (size_t)BN_TOTAL * 256 * 4);   // 128 KB
    char*   tb      = ws + (size_t)BN_TOTAL * 256 * 4 + (size_t)BN_TOTAL * 4;
    bf16x8* fragsE  = (bf16x8*)tb;               // 8 KB
    bf16x8* fragsF  = (bf16x8*)(tb + 8192);      // 64 KB
    bf16x8* fragsG1 = (bf16x8*)(tb + 8192 + 65536);          // 16 KB
    bf16x8* fragsG2 = (bf16x8*)(tb + 8192 + 65536 + 16384);  // 16 KB

    k_prep<<<13, 256, 0, stream>>>(We1, We2, Wf0, Wf1, Wf2,
                                   fragsE, fragsF, fragsG1, fragsG2);
    k_emb_mfma<<<BN_TOTAL / 2, 128, 0, stream>>>(Sg, R, We0, be0, be1, be2, fragsE, Dm);
    k_fit4<<<BN_TOTAL / 64, 256, 0, stream>>>(Dm, fragsF, fragsG1, fragsG2,
                                              bf0, bf1, bf2, Wf3, bf3, Q);
    k_mean<<<BB, 256, 0, stream>>>(Q, (float*)d_out);
}

// Round 17
// 65.673 us; speedup vs baseline: 1.0192x; 1.0192x over previous
//
#include <hip/hip_runtime.h>

// Problem constants
#define BB 64
#define NN 512
#define MM 30
#define E2 4
#define NE 32
#define NE4 8
#define NF 64
#define BN_TOTAL (BB * NN)   // 32768
#define TP2 40                // padded row (u16) of the bf16 h1 tile: stride 80 B
#define HP 65                 // padded row (floats) of HT tiles in k_fit

typedef __attribute__((ext_vector_type(8))) short bf16x8;
typedef __attribute__((ext_vector_type(4))) float vf4;

// Fast activations: raw v_rcp_f32 (~1 ulp) instead of the IEEE div sequence.
__device__ __forceinline__ float frcp(float x) { return __builtin_amdgcn_rcpf(x); }
__device__ __forceinline__ float fsig(float x)  { return frcp(1.0f + __expf(-x)); }
__device__ __forceinline__ float ftanh(float x) { return 1.0f - 2.0f * frcp(1.0f + __expf(2.0f * x)); }

union fragu { unsigned u[4]; bf16x8 v; };

__device__ __forceinline__ unsigned cvt_pk_bf16(float a, float b) {
    unsigned r;
    asm("v_cvt_pk_bf16_f32 %0, %1, %2" : "=v"(r) : "v"(a), "v"(b));
    return r;
}
__device__ __forceinline__ float lo16f(unsigned u) { return __uint_as_float(u << 16); }
__device__ __forceinline__ float hi16f(unsigned u) { return __uint_as_float(u & 0xFFFF0000u); }

// Split 8 fp32 (a.xyzw, b.xyzw) into hi/lo bf16 fragments (RNE via v_cvt_pk_bf16_f32).
__device__ __forceinline__ void split8v(vf4 a, vf4 b, bf16x8& hi, bf16x8& lo) {
    fragu H, L;
    H.u[0] = cvt_pk_bf16(a.x, a.y);
    H.u[1] = cvt_pk_bf16(a.z, a.w);
    H.u[2] = cvt_pk_bf16(b.x, b.y);
    H.u[3] = cvt_pk_bf16(b.z, b.w);
    L.u[0] = cvt_pk_bf16(a.x - lo16f(H.u[0]), a.y - hi16f(H.u[0]));
    L.u[1] = cvt_pk_bf16(a.z - lo16f(H.u[1]), a.w - hi16f(H.u[1]));
    L.u[2] = cvt_pk_bf16(b.x - lo16f(H.u[2]), b.y - hi16f(H.u[2]));
    L.u[3] = cvt_pk_bf16(b.z - lo16f(H.u[3]), b.w - hi16f(H.u[3]));
    hi = H.v; lo = L.v;
}

// Pack 8 fp32 to single bf16 frag (RNE), no lo term — activation A-frags
// whose per-row rounding noise attenuates ~sqrt(512) in the final mean.
__device__ __forceinline__ bf16x8 pack8(vf4 a, vf4 b) {
    fragu H;
    H.u[0] = cvt_pk_bf16(a.x, a.y);
    H.u[1] = cvt_pk_bf16(a.z, a.w);
    H.u[2] = cvt_pk_bf16(b.x, b.y);
    H.u[3] = cvt_pk_bf16(b.z, b.w);
    return H.v;
}

// 3-term split-precision MFMA: C += A*B with A=Ah+Al, B=Bh+Bl (lolo dropped).
__device__ __forceinline__ vf4 mm3(bf16x8 ah, bf16x8 al, bf16x8 bh, bf16x8 bl, vf4 c) {
    c = __builtin_amdgcn_mfma_f32_16x16x32_bf16(ah, bh, c, 0, 0, 0);
    c = __builtin_amdgcn_mfma_f32_16x16x32_bf16(ah, bl, c, 0, 0, 0);
    c = __builtin_amdgcn_mfma_f32_16x16x32_bf16(al, bh, c, 0, 0, 0);
    return c;
}

// 2-term: A single bf16 (activation), B split (weights).
__device__ __forceinline__ vf4 mm2(bf16x8 a, bf16x8 bh, bf16x8 bl, vf4 c) {
    c = __builtin_amdgcn_mfma_f32_16x16x32_bf16(a, bh, c, 0, 0, 0);
    c = __builtin_amdgcn_mfma_f32_16x16x32_bf16(a, bl, c, 0, 0, 0);
    return c;
}

__device__ __forceinline__ vf4 ld4(const float* p) { return *(const vf4*)p; }

// ---------------------------------------------------------------------------
// K0: one-time weight-fragment precompute (unchanged).
// ---------------------------------------------------------------------------
__global__ __launch_bounds__(256) void k_prep(
    const float* __restrict__ We1, const float* __restrict__ We2,
    const float* __restrict__ Wf0, const float* __restrict__ Wf1,
    const float* __restrict__ Wf2,
    bf16x8* __restrict__ fragsE, bf16x8* __restrict__ fragsF,
    bf16x8* __restrict__ fragsG1, bf16x8* __restrict__ fragsG2)
{
    const int tid  = threadIdx.x;
    const int l    = tid & 63;
    const int row0 = l & 15;
    const int grp  = l >> 4;
    const int bid  = blockIdx.x;

    if (bid < 8) {
        const int combo = bid * 4 + (tid >> 6);          // 0..31
        const int k  = combo >> 2;
        const int nt = combo & 3;
        const float* wp = Wf0 + (size_t)(k * 32 + grp * 8) * NF + nt * 16 + row0;
        vf4 x0 = { wp[0],      wp[NF],     wp[2 * NF], wp[3 * NF] };
        vf4 x1 = { wp[4 * NF], wp[5 * NF], wp[6 * NF], wp[7 * NF] };
        bf16x8 h, lo;
        split8v(x0, x1, h, lo);
        fragsF[(combo * 2 + 0) * 64 + l] = h;
        fragsF[(combo * 2 + 1) * 64 + l] = lo;
    } else if (bid < 12) {
        const int layer = (bid - 8) >> 1;                // 0 -> Wf1, 1 -> Wf2
        const int combo = ((bid - 8) & 1) * 4 + (tid >> 6);   // 0..7
        const int ktile = combo >> 2;
        const int nt    = combo & 3;
        const float* W  = layer ? Wf2 : Wf1;
        bf16x8* out     = layer ? fragsG2 : fragsG1;
        const float* wp = W + (size_t)(ktile * 32 + grp * 8) * NF + nt * 16 + row0;
        vf4 x0 = { wp[0],      wp[NF],     wp[2 * NF], wp[3 * NF] };
        vf4 x1 = { wp[4 * NF], wp[5 * NF], wp[6 * NF], wp[7 * NF] };
        bf16x8 h, lo;
        split8v(x0, x1, h, lo);
        out[(combo * 2 + 0) * 64 + l] = h;
        out[(combo * 2 + 1) * 64 + l] = lo;
    } else if (tid < 64) {
#pragma unroll
        for (int nt = 0; nt < 2; ++nt) {
            const float* wp = We1 + (size_t)(grp * 8) * NE + nt * 16 + row0;
            vf4 x0 = { wp[0],      wp[NE],     wp[2 * NE], wp[3 * NE] };
            vf4 x1 = { wp[4 * NE], wp[5 * NE], wp[6 * NE], wp[7 * NE] };
            bf16x8 h, lo;
            split8v(x0, x1, h, lo);
            fragsE[(0 + nt) * 64 + l] = h;
            fragsE[(2 + nt) * 64 + l] = lo;
            const float* wq = We2 + (size_t)(grp * 8) * NE + nt * 16 + row0;
            vf4 y0 = { wq[0],      wq[NE],     wq[2 * NE], wq[3 * NE] };
            vf4 y1 = { wq[4 * NE], wq[5 * NE], wq[6 * NE], wq[7 * NE] };
            split8v(y0, y1, h, lo);
            fragsE[(4 + nt) * 64 + l] = h;
            fragsE[(6 + nt) * 64 + l] = lo;
        }
    }
}

// ---------------------------------------------------------------------------
// K1 v9 (MFMA): one wave per (b,n) pair, 2-wave blocks.
// = round-16 (known-good) emb + ONE change: layer-1 A-frag is single bf16
// (pack8 of sigmoid output, lo dropped) and layer 1 uses mm2 (8 MFMAs vs 12).
// Everything else — T16 bf16-h1 tile, mm2 layer 2, Bm/D epilogue — is the
// bench-validated round-13/16 code, bit-identical.
// ---------------------------------------------------------------------------
__global__ __launch_bounds__(128) void k_emb_mfma(
    const float* __restrict__ Sg, const float* __restrict__ R,
    const float* __restrict__ We0, const float* __restrict__ be0,
    const float* __restrict__ be1, const float* __restrict__ be2,
    const bf16x8* __restrict__ frags,
    float* __restrict__ Dout)
{
    __shared__ unsigned short T16[2][32 * TP2];   // bf16 h1 tile, 2560 B/wave
    __shared__ vf4 Rl[2][32];                     // R rows (30,31 zeroed)

    const int tid  = threadIdx.x;
    const int w    = tid >> 6;
    const int l    = tid & 63;
    const int row0 = l & 15;
    const int grp  = l >> 4;
    const int pair = blockIdx.x * 2 + w;

    // ---- stage R (rows 30,31 = 0) ----
    if (l < 32) {
        vf4 rv = 0.f;
        if (l < MM) rv = ld4(R + ((size_t)pair * MM + l) * 4);
        Rl[w][l] = rv;
    }

    // ---- precomputed B-fragments: 8 x b128 ----
    bf16x8 B1h[2], B1l[2], B2h[2], B2l[2];
#pragma unroll
    for (int nt = 0; nt < 2; ++nt) {
        B1h[nt] = frags[(0 + nt) * 64 + l];
        B1l[nt] = frags[(2 + nt) * 64 + l];
        B2h[nt] = frags[(4 + nt) * 64 + l];
        B2l[nt] = frags[(6 + nt) * 64 + l];
    }

    // ---- layer-0 weights (lane-indexed, L1-resident) ----
    vf4 w0[4][2];
#pragma unroll
    for (int i = 0; i < 4; ++i) {
        w0[i][0] = ld4(We0 + i * NE + grp * 8);
        w0[i][1] = ld4(We0 + i * NE + grp * 8 + 4);
    }
    const vf4 b0a = ld4(be0 + grp * 8);
    const vf4 b0b = ld4(be0 + grp * 8 + 4);
    const float bias1[2] = { be1[row0], be1[row0 + 16] };
    const float bias2[2] = { be2[row0], be2[row0 + 16] };

    // ---- layer 0: 4 -> 32, sigmoid; single-bf16 A-frags for layer 1 ----
    bf16x8 A1[2];
#pragma unroll
    for (int t = 0; t < 2; ++t) {
        const int p = 16 * t + row0;
        vf4 s = 0.f;
        if (p < MM) s = ld4(Sg + ((size_t)pair * MM + p) * 4);
        vf4 acc0 = b0a + s.x * w0[0][0] + s.y * w0[1][0] + s.z * w0[2][0] + s.w * w0[3][0];
        vf4 acc1 = b0b + s.x * w0[0][1] + s.y * w0[1][1] + s.z * w0[2][1] + s.w * w0[3][1];
#pragma unroll
        for (int e = 0; e < 4; ++e) { acc0[e] = fsig(acc0[e]); acc1[e] = fsig(acc1[e]); }
        A1[t] = pack8(acc0, acc1);
    }

    // ---- layer 1 MFMA (2-term, bias in accumulator init) ----
    vf4 H1[2][2];
#pragma unroll
    for (int t = 0; t < 2; ++t)
#pragma unroll
        for (int nt = 0; nt < 2; ++nt) {
            vf4 c = bias1[nt];
            H1[t][nt] = mm2(A1[t], B1h[nt], B1l[nt], c);
        }

    // ---- tanh -> bf16 -> transposed u16 tile ----
#pragma unroll
    for (int t = 0; t < 2; ++t)
#pragma unroll
        for (int nt = 0; nt < 2; ++nt)
#pragma unroll
            for (int e = 0; e < 4; ++e) {
                const float v = ftanh(H1[t][nt][e]);
                T16[w][(grp * 4 + e + 16 * t) * TP2 + row0 + 16 * nt] =
                    (unsigned short)(cvt_pk_bf16(v, v) & 0xFFFFu);
            }

    // ---- layer-2 A-frags: direct b128 read (16B-aligned: 80*(16t+row0)+16g) ----
    bf16x8 A2[2];
#pragma unroll
    for (int t = 0; t < 2; ++t)
        A2[t] = *(const bf16x8*)&T16[w][(16 * t + row0) * TP2 + grp * 8];

    // ---- layer 2 MFMA (2-term): G = h1' @ We2 + be2 ----
    vf4 G[2][2];
#pragma unroll
    for (int t = 0; t < 2; ++t)
#pragma unroll
        for (int nt = 0; nt < 2; ++nt) {
            vf4 c = bias2[nt];
            G[t][nt] = mm2(A2[t], B2h[nt], B2l[nt], c);
        }

    // ---- Bm[l][col] = sum_m R[m][l]*G[m][col] ----
    float bm[4][2] = {{0.f, 0.f}, {0.f, 0.f}, {0.f, 0.f}, {0.f, 0.f}};
#pragma unroll
    for (int t = 0; t < 2; ++t)
#pragma unroll
        for (int e = 0; e < 4; ++e) {
            const int rrow = grp * 4 + e + 16 * t;
            const vf4 r4 = Rl[w][rrow];
#pragma unroll
            for (int nt = 0; nt < 2; ++nt) {
                const float gv = G[t][nt][e];
                bm[0][nt] += r4.x * gv;
                bm[1][nt] += r4.y * gv;
                bm[2][nt] += r4.z * gv;
                bm[3][nt] += r4.w * gv;
            }
        }
    float bmv[4][2];
#pragma unroll
    for (int li = 0; li < 4; ++li)
#pragma unroll
        for (int nt = 0; nt < 2; ++nt) {
            float v = bm[li][nt];
            v += __shfl_xor(v, 16);
            v += __shfl_xor(v, 32);
            bmv[li][nt] = v;
        }

    // ---- D[k][n] = sum_l Bm[l][k]*Bm[l][n]; lane: k=2grp+kk, n=row0+16nt ----
    float d[2][2] = {{0.f, 0.f}, {0.f, 0.f}};
#pragma unroll
    for (int kk = 0; kk < 2; ++kk) {
        const int src = grp * 2 + kk;
#pragma unroll
        for (int li = 0; li < 4; ++li) {
            const float a = __shfl(bmv[li][0], src);
#pragma unroll
            for (int nt = 0; nt < 2; ++nt) d[kk][nt] += a * bmv[li][nt];
        }
    }

    float* __restrict__ dp = Dout + (size_t)pair * 256;
#pragma unroll
    for (int kk = 0; kk < 2; ++kk)
#pragma unroll
        for (int nt = 0; nt < 2; ++nt)
            dp[(grp * 2 + kk) * NE + nt * 16 + row0] = d[kk][nt];
}

// ---------------------------------------------------------------------------
// K2 v5: fit MLP — all layers MFMA (round-13/16 state, UNCHANGED: f32 HT
// tiles, 3-term splits). The bf16-tile variant (rounds 14/15) is dead — it
// failed correctness twice and the bug was never localized.
// ---------------------------------------------------------------------------
__global__ __launch_bounds__(256) void k_fit4(
    const float* __restrict__ D, const bf16x8* __restrict__ fragsF,
    const bf16x8* __restrict__ fragsG1, const bf16x8* __restrict__ fragsG2,
    const float* __restrict__ bf0, const float* __restrict__ bf1,
    const float* __restrict__ bf2,
    const float* __restrict__ Wf3, const float* __restrict__ bf3,
    float* __restrict__ Q)
{
    __shared__ float HT0[64 * HP];   // 16.25 KB, [feat][row]
    __shared__ float HT1[64 * HP];   // 16.25 KB, [feat][row]
    __shared__ float Qp[64];

    const int tid  = threadIdx.x;
    const int wv   = tid >> 6;
    const int l    = tid & 63;
    const int row0 = l & 15;
    const int grp  = l >> 4;

    // ---------------- layer 0 (MFMA): D[256] -> 64, tanh ----------------
    {
        const float* __restrict__ drow =
            D + (size_t)(blockIdx.x * 64 + wv * 16 + row0) * 256;

        vf4 c[4];
#pragma unroll
        for (int nt = 0; nt < 4; ++nt) c[nt] = bf0[nt * 16 + row0];

#pragma unroll
        for (int k = 0; k < 8; ++k) {
            vf4 x0 = ld4(drow + k * 32 + grp * 8);
            vf4 x1 = ld4(drow + k * 32 + grp * 8 + 4);
            bf16x8 ah, al;
            split8v(x0, x1, ah, al);
#pragma unroll
            for (int nt = 0; nt < 4; ++nt) {
                const int combo = k * 4 + nt;
                c[nt] = mm3(ah, al, fragsF[(combo * 2 + 0) * 64 + l],
                                    fragsF[(combo * 2 + 1) * 64 + l], c[nt]);
            }
        }
#pragma unroll
        for (int nt = 0; nt < 4; ++nt)
#pragma unroll
            for (int e = 0; e < 4; ++e)
                HT0[(nt * 16 + row0) * HP + wv * 16 + grp * 4 + e] = ftanh(c[nt][e]);
    }

    // ---------------- layer 1 (MFMA): 64 -> 64, sigmoid ----------------
    {
        vf4 c[4];
#pragma unroll
        for (int nt = 0; nt < 4; ++nt) c[nt] = bf1[nt * 16 + row0];
#pragma unroll
        for (int ktile = 0; ktile < 2; ++ktile) {
            vf4 x0, x1;
#pragma unroll
            for (int e = 0; e < 4; ++e) {
                x0[e] = HT0[(ktile * 32 + grp * 8 + e) * HP + wv * 16 + row0];
                x1[e] = HT0[(ktile * 32 + grp * 8 + 4 + e) * HP + wv * 16 + row0];
            }
            bf16x8 ah, al;
            split8v(x0, x1, ah, al);
#pragma unroll
            for (int nt = 0; nt < 4; ++nt) {
                const int combo = ktile * 4 + nt;
                c[nt] = mm3(ah, al, fragsG1[(combo * 2 + 0) * 64 + l],
                                    fragsG1[(combo * 2 + 1) * 64 + l], c[nt]);
            }
        }
#pragma unroll
        for (int nt = 0; nt < 4; ++nt)
#pragma unroll
            for (int e = 0; e < 4; ++e)
                HT1[(nt * 16 + row0) * HP + wv * 16 + grp * 4 + e] = fsig(c[nt][e]);
    }

    // ---------------- layer 2 (MFMA): 64 -> 64 (tanh in L3) -------------
    vf4 c2[4];
    {
#pragma unroll
        for (int nt = 0; nt < 4; ++nt) c2[nt] = bf2[nt * 16 + row0];
#pragma unroll
        for (int ktile = 0; ktile < 2; ++ktile) {
            vf4 x0, x1;
#pragma unroll
            for (int e = 0; e < 4; ++e) {
                x0[e] = HT1[(ktile * 32 + grp * 8 + e) * HP + wv * 16 + row0];
                x1[e] = HT1[(ktile * 32 + grp * 8 + 4 + e) * HP + wv * 16 + row0];
            }
            bf16x8 ah, al;
            split8v(x0, x1, ah, al);
#pragma unroll
            for (int nt = 0; nt < 4; ++nt) {
                const int combo = ktile * 4 + nt;
                c2[nt] = mm3(ah, al, fragsG2[(combo * 2 + 0) * 64 + l],
                                     fragsG2[(combo * 2 + 1) * 64 + l], c2[nt]);
            }
        }
    }

    // ---------------- layer 3: tanh + dot with Wf3, reduce over row0 ----
    {
        float p[4] = {0.f, 0.f, 0.f, 0.f};   // rows wv*16 + grp*4 + e
#pragma unroll
        for (int nt = 0; nt < 4; ++nt) {
            const float w3 = Wf3[nt * 16 + row0];
#pragma unroll
            for (int e = 0; e < 4; ++e) p[e] += ftanh(c2[nt][e]) * w3;
        }
#pragma unroll
        for (int e = 0; e < 4; ++e) {
            float v = p[e];
            v += __shfl_xor(v, 1);
            v += __shfl_xor(v, 2);
            v += __shfl_xor(v, 4);
            v += __shfl_xor(v, 8);
            if (row0 == 0) Qp[wv * 16 + grp * 4 + e] = v;
        }
    }
    __syncthreads();

    if (tid < 64)
        Q[(size_t)blockIdx.x * 64 + tid] = bf3[0] + Qp[tid];
}

// ---------------------------------------------------------------------------
// K3: deterministic mean over N per batch element.
// ---------------------------------------------------------------------------
__global__ __launch_bounds__(256) void k_mean(const float* __restrict__ Q,
                                              float* __restrict__ out)
{
    __shared__ float s[256];
    const int b = blockIdx.x;
    const int t = threadIdx.x;
    float v = Q[b * NN + t] + Q[b * NN + 256 + t];
    s[t] = v;
    __syncthreads();
#pragma unroll
    for (int off = 128; off > 0; off >>= 1) {
        if (t < off) s[t] += s[t + off];
        __syncthreads();
    }
    if (t == 0) out[b] = s[0] * (1.0f / (float)NN);
}

// ---------------------------------------------------------------------------
extern "C" void kernel_launch(void* const* d_in, const int* in_sizes, int n_in,
                              void* d_out, int out_size, void* d_ws, size_t ws_size,
                              hipStream_t stream)
{
    const float* Sg  = (const float*)d_in[0];
    const float* R   = (const float*)d_in[1];
    const float* We0 = (const float*)d_in[2];
    const float* be0 = (const float*)d_in[3];
    const float* We1 = (const float*)d_in[4];
    const float* be1 = (const float*)d_in[5];
    const float* We2 = (const float*)d_in[6];
    const float* be2 = (const float*)d_in[7];
    const float* Wf0 = (const float*)d_in[8];
    const float* bf0 = (const float*)d_in[9];
    const float* Wf1 = (const float*)d_in[10];
    const float* bf1 = (const float*)d_in[11];
    const float* Wf2 = (const float*)d_in[12];
    const float* bf2 = (const float*)d_in[13];
    const float* Wf3 = (const float*)d_in[14];
    const float* bf3 = (const float*)d_in[15];

    char* ws = (char*)d_ws;
    float*  Dm      = (float*)ws;                                  // 33.55 MB
    float*  Q       = (float*)(ws + (size_t)BN_TOTAL * 256 * 4);   // 128 KB
    char*   tb      = ws + (size_t)BN_TOTAL * 256 * 4 + (size_t)BN_TOTAL * 4;
    bf16x8* fragsE  = (bf16x8*)tb;               // 8 KB
    bf16x8* fragsF  = (bf16x8*)(tb + 8192);      // 64 KB
    bf16x8* fragsG1 = (bf16x8*)(tb + 8192 + 65536);          // 16 KB
    bf16x8* fragsG2 = (bf16x8*)(tb + 8192 + 65536 + 16384);  // 16 KB

    k_prep<<<13, 256, 0, stream>>>(We1, We2, Wf0, Wf1, Wf2,
                                   fragsE, fragsF, fragsG1, fragsG2);
    k_emb_mfma<<<BN_TOTAL / 2, 128, 0, stream>>>(Sg, R, We0, be0, be1, be2, fragsE, Dm);
    k_fit4<<<BN_TOTAL / 64, 256, 0, stream>>>(Dm, fragsF, fragsG1, fragsG2,
                                              bf0, bf1, bf2, Wf3, bf3, Q);
    k_mean<<<BB, 256, 0, stream>>>(Q, (float*)d_out);
}

// Round 19
// 65.514 us; speedup vs baseline: 1.0217x; 1.0024x over previous
//
#include <hip/hip_runtime.h>

// Problem constants
#define BB 64
#define NN 512
#define MM 30
#define E2 4
#define NE 32
#define NE4 8
#define NF 64
#define BN_TOTAL (BB * NN)   // 32768
#define TP2 40                // padded row (u16) of the bf16 h1 tile: stride 80 B
#define HP 65                 // padded row (floats) of HT tiles in k_fit

typedef __attribute__((ext_vector_type(8))) short bf16x8;
typedef __attribute__((ext_vector_type(4))) float vf4;

// Fast activations: raw v_rcp_f32 (~1 ulp) instead of the IEEE div sequence.
__device__ __forceinline__ float frcp(float x) { return __builtin_amdgcn_rcpf(x); }
__device__ __forceinline__ float fsig(float x)  { return frcp(1.0f + __expf(-x)); }
__device__ __forceinline__ float ftanh(float x) { return 1.0f - 2.0f * frcp(1.0f + __expf(2.0f * x)); }

union fragu { unsigned u[4]; bf16x8 v; };

__device__ __forceinline__ unsigned cvt_pk_bf16(float a, float b) {
    unsigned r;
    asm("v_cvt_pk_bf16_f32 %0, %1, %2" : "=v"(r) : "v"(a), "v"(b));
    return r;
}
__device__ __forceinline__ float lo16f(unsigned u) { return __uint_as_float(u << 16); }
__device__ __forceinline__ float hi16f(unsigned u) { return __uint_as_float(u & 0xFFFF0000u); }

// Split 8 fp32 (a.xyzw, b.xyzw) into hi/lo bf16 fragments (RNE via v_cvt_pk_bf16_f32).
__device__ __forceinline__ void split8v(vf4 a, vf4 b, bf16x8& hi, bf16x8& lo) {
    fragu H, L;
    H.u[0] = cvt_pk_bf16(a.x, a.y);
    H.u[1] = cvt_pk_bf16(a.z, a.w);
    H.u[2] = cvt_pk_bf16(b.x, b.y);
    H.u[3] = cvt_pk_bf16(b.z, b.w);
    L.u[0] = cvt_pk_bf16(a.x - lo16f(H.u[0]), a.y - hi16f(H.u[0]));
    L.u[1] = cvt_pk_bf16(a.z - lo16f(H.u[1]), a.w - hi16f(H.u[1]));
    L.u[2] = cvt_pk_bf16(b.x - lo16f(H.u[2]), b.y - hi16f(H.u[2]));
    L.u[3] = cvt_pk_bf16(b.z - lo16f(H.u[3]), b.w - hi16f(H.u[3]));
    hi = H.v; lo = L.v;
}

// Pack 8 fp32 to single bf16 frag (RNE), no lo term — activation A-frags
// whose per-row rounding noise attenuates ~sqrt(512) in the final mean.
__device__ __forceinline__ bf16x8 pack8(vf4 a, vf4 b) {
    fragu H;
    H.u[0] = cvt_pk_bf16(a.x, a.y);
    H.u[1] = cvt_pk_bf16(a.z, a.w);
    H.u[2] = cvt_pk_bf16(b.x, b.y);
    H.u[3] = cvt_pk_bf16(b.z, b.w);
    return H.v;
}

// 3-term split-precision MFMA: C += A*B with A=Ah+Al, B=Bh+Bl (lolo dropped).
__device__ __forceinline__ vf4 mm3(bf16x8 ah, bf16x8 al, bf16x8 bh, bf16x8 bl, vf4 c) {
    c = __builtin_amdgcn_mfma_f32_16x16x32_bf16(ah, bh, c, 0, 0, 0);
    c = __builtin_amdgcn_mfma_f32_16x16x32_bf16(ah, bl, c, 0, 0, 0);
    c = __builtin_amdgcn_mfma_f32_16x16x32_bf16(al, bh, c, 0, 0, 0);
    return c;
}

// 2-term: A single bf16 (activation), B split (weights).
__device__ __forceinline__ vf4 mm2(bf16x8 a, bf16x8 bh, bf16x8 bl, vf4 c) {
    c = __builtin_amdgcn_mfma_f32_16x16x32_bf16(a, bh, c, 0, 0, 0);
    c = __builtin_amdgcn_mfma_f32_16x16x32_bf16(a, bl, c, 0, 0, 0);
    return c;
}

__device__ __forceinline__ vf4 ld4(const float* p) { return *(const vf4*)p; }

// ---------------------------------------------------------------------------
// K0: one-time weight-fragment precompute (unchanged).
// ---------------------------------------------------------------------------
__global__ __launch_bounds__(256) void k_prep(
    const float* __restrict__ We1, const float* __restrict__ We2,
    const float* __restrict__ Wf0, const float* __restrict__ Wf1,
    const float* __restrict__ Wf2,
    bf16x8* __restrict__ fragsE, bf16x8* __restrict__ fragsF,
    bf16x8* __restrict__ fragsG1, bf16x8* __restrict__ fragsG2)
{
    const int tid  = threadIdx.x;
    const int l    = tid & 63;
    const int row0 = l & 15;
    const int grp  = l >> 4;
    const int bid  = blockIdx.x;

    if (bid < 8) {
        const int combo = bid * 4 + (tid >> 6);          // 0..31
        const int k  = combo >> 2;
        const int nt = combo & 3;
        const float* wp = Wf0 + (size_t)(k * 32 + grp * 8) * NF + nt * 16 + row0;
        vf4 x0 = { wp[0],      wp[NF],     wp[2 * NF], wp[3 * NF] };
        vf4 x1 = { wp[4 * NF], wp[5 * NF], wp[6 * NF], wp[7 * NF] };
        bf16x8 h, lo;
        split8v(x0, x1, h, lo);
        fragsF[(combo * 2 + 0) * 64 + l] = h;
        fragsF[(combo * 2 + 1) * 64 + l] = lo;
    } else if (bid < 12) {
        const int layer = (bid - 8) >> 1;                // 0 -> Wf1, 1 -> Wf2
        const int combo = ((bid - 8) & 1) * 4 + (tid >> 6);   // 0..7
        const int ktile = combo >> 2;
        const int nt    = combo & 3;
        const float* W  = layer ? Wf2 : Wf1;
        bf16x8* out     = layer ? fragsG2 : fragsG1;
        const float* wp = W + (size_t)(ktile * 32 + grp * 8) * NF + nt * 16 + row0;
        vf4 x0 = { wp[0],      wp[NF],     wp[2 * NF], wp[3 * NF] };
        vf4 x1 = { wp[4 * NF], wp[5 * NF], wp[6 * NF], wp[7 * NF] };
        bf16x8 h, lo;
        split8v(x0, x1, h, lo);
        out[(combo * 2 + 0) * 64 + l] = h;
        out[(combo * 2 + 1) * 64 + l] = lo;
    } else if (tid < 64) {
#pragma unroll
        for (int nt = 0; nt < 2; ++nt) {
            const float* wp = We1 + (size_t)(grp * 8) * NE + nt * 16 + row0;
            vf4 x0 = { wp[0],      wp[NE],     wp[2 * NE], wp[3 * NE] };
            vf4 x1 = { wp[4 * NE], wp[5 * NE], wp[6 * NE], wp[7 * NE] };
            bf16x8 h, lo;
            split8v(x0, x1, h, lo);
            fragsE[(0 + nt) * 64 + l] = h;
            fragsE[(2 + nt) * 64 + l] = lo;
            const float* wq = We2 + (size_t)(grp * 8) * NE + nt * 16 + row0;
            vf4 y0 = { wq[0],      wq[NE],     wq[2 * NE], wq[3 * NE] };
            vf4 y1 = { wq[4 * NE], wq[5 * NE], wq[6 * NE], wq[7 * NE] };
            split8v(y0, y1, h, lo);
            fragsE[(4 + nt) * 64 + l] = h;
            fragsE[(6 + nt) * 64 + l] = lo;
        }
    }
}

// ---------------------------------------------------------------------------
// K1 v9 (MFMA): one wave per (b,n) pair, 2-wave blocks — round-17 state
// (validated: absmax 1.2e-4, k_emb ~46-48 µs). 16-wave geometry (round 18)
// FAILED correctness and is dead; 2-wave is the proven envelope.
// ---------------------------------------------------------------------------
__global__ __launch_bounds__(128) void k_emb_mfma(
    const float* __restrict__ Sg, const float* __restrict__ R,
    const float* __restrict__ We0, const float* __restrict__ be0,
    const float* __restrict__ be1, const float* __restrict__ be2,
    const bf16x8* __restrict__ frags,
    float* __restrict__ Dout)
{
    __shared__ unsigned short T16[2][32 * TP2];   // bf16 h1 tile, 2560 B/wave
    __shared__ vf4 Rl[2][32];                     // R rows (30,31 zeroed)

    const int tid  = threadIdx.x;
    const int w    = tid >> 6;
    const int l    = tid & 63;
    const int row0 = l & 15;
    const int grp  = l >> 4;
    const int pair = blockIdx.x * 2 + w;

    // ---- stage R (rows 30,31 = 0) ----
    if (l < 32) {
        vf4 rv = 0.f;
        if (l < MM) rv = ld4(R + ((size_t)pair * MM + l) * 4);
        Rl[w][l] = rv;
    }

    // ---- precomputed B-fragments: 8 x b128 ----
    bf16x8 B1h[2], B1l[2], B2h[2], B2l[2];
#pragma unroll
    for (int nt = 0; nt < 2; ++nt) {
        B1h[nt] = frags[(0 + nt) * 64 + l];
        B1l[nt] = frags[(2 + nt) * 64 + l];
        B2h[nt] = frags[(4 + nt) * 64 + l];
        B2l[nt] = frags[(6 + nt) * 64 + l];
    }

    // ---- layer-0 weights (lane-indexed, L1-resident) ----
    vf4 w0[4][2];
#pragma unroll
    for (int i = 0; i < 4; ++i) {
        w0[i][0] = ld4(We0 + i * NE + grp * 8);
        w0[i][1] = ld4(We0 + i * NE + grp * 8 + 4);
    }
    const vf4 b0a = ld4(be0 + grp * 8);
    const vf4 b0b = ld4(be0 + grp * 8 + 4);
    const float bias1[2] = { be1[row0], be1[row0 + 16] };
    const float bias2[2] = { be2[row0], be2[row0 + 16] };

    // ---- layer 0: 4 -> 32, sigmoid; single-bf16 A-frags for layer 1 ----
    bf16x8 A1[2];
#pragma unroll
    for (int t = 0; t < 2; ++t) {
        const int p = 16 * t + row0;
        vf4 s = 0.f;
        if (p < MM) s = ld4(Sg + ((size_t)pair * MM + p) * 4);
        vf4 acc0 = b0a + s.x * w0[0][0] + s.y * w0[1][0] + s.z * w0[2][0] + s.w * w0[3][0];
        vf4 acc1 = b0b + s.x * w0[0][1] + s.y * w0[1][1] + s.z * w0[2][1] + s.w * w0[3][1];
#pragma unroll
        for (int e = 0; e < 4; ++e) { acc0[e] = fsig(acc0[e]); acc1[e] = fsig(acc1[e]); }
        A1[t] = pack8(acc0, acc1);
    }

    // ---- layer 1 MFMA (2-term, bias in accumulator init) ----
    vf4 H1[2][2];
#pragma unroll
    for (int t = 0; t < 2; ++t)
#pragma unroll
        for (int nt = 0; nt < 2; ++nt) {
            vf4 c = bias1[nt];
            H1[t][nt] = mm2(A1[t], B1h[nt], B1l[nt], c);
        }

    // ---- tanh -> bf16 -> transposed u16 tile ----
#pragma unroll
    for (int t = 0; t < 2; ++t)
#pragma unroll
        for (int nt = 0; nt < 2; ++nt)
#pragma unroll
            for (int e = 0; e < 4; ++e) {
                const float v = ftanh(H1[t][nt][e]);
                T16[w][(grp * 4 + e + 16 * t) * TP2 + row0 + 16 * nt] =
                    (unsigned short)(cvt_pk_bf16(v, v) & 0xFFFFu);
            }

    // ---- layer-2 A-frags: direct b128 read (16B-aligned: 80*(16t+row0)+16g) ----
    bf16x8 A2[2];
#pragma unroll
    for (int t = 0; t < 2; ++t)
        A2[t] = *(const bf16x8*)&T16[w][(16 * t + row0) * TP2 + grp * 8];

    // ---- layer 2 MFMA (2-term): G = h1' @ We2 + be2 ----
    vf4 G[2][2];
#pragma unroll
    for (int t = 0; t < 2; ++t)
#pragma unroll
        for (int nt = 0; nt < 2; ++nt) {
            vf4 c = bias2[nt];
            G[t][nt] = mm2(A2[t], B2h[nt], B2l[nt], c);
        }

    // ---- Bm[l][col] = sum_m R[m][l]*G[m][col] ----
    float bm[4][2] = {{0.f, 0.f}, {0.f, 0.f}, {0.f, 0.f}, {0.f, 0.f}};
#pragma unroll
    for (int t = 0; t < 2; ++t)
#pragma unroll
        for (int e = 0; e < 4; ++e) {
            const int rrow = grp * 4 + e + 16 * t;
            const vf4 r4 = Rl[w][rrow];
#pragma unroll
            for (int nt = 0; nt < 2; ++nt) {
                const float gv = G[t][nt][e];
                bm[0][nt] += r4.x * gv;
                bm[1][nt] += r4.y * gv;
                bm[2][nt] += r4.z * gv;
                bm[3][nt] += r4.w * gv;
            }
        }
    float bmv[4][2];
#pragma unroll
    for (int li = 0; li < 4; ++li)
#pragma unroll
        for (int nt = 0; nt < 2; ++nt) {
            float v = bm[li][nt];
            v += __shfl_xor(v, 16);
            v += __shfl_xor(v, 32);
            bmv[li][nt] = v;
        }

    // ---- D[k][n] = sum_l Bm[l][k]*Bm[l][n]; lane: k=2grp+kk, n=row0+16nt ----
    float d[2][2] = {{0.f, 0.f}, {0.f, 0.f}};
#pragma unroll
    for (int kk = 0; kk < 2; ++kk) {
        const int src = grp * 2 + kk;
#pragma unroll
        for (int li = 0; li < 4; ++li) {
            const float a = __shfl(bmv[li][0], src);
#pragma unroll
            for (int nt = 0; nt < 2; ++nt) d[kk][nt] += a * bmv[li][nt];
        }
    }

    float* __restrict__ dp = Dout + (size_t)pair * 256;
#pragma unroll
    for (int kk = 0; kk < 2; ++kk)
#pragma unroll
        for (int nt = 0; nt < 2; ++nt)
            dp[(grp * 2 + kk) * NE + nt * 16 + row0] = d[kk][nt];
}

// ---------------------------------------------------------------------------
// K2 v5: fit MLP — all layers MFMA (round-13/16/17 state, UNCHANGED).
// ---------------------------------------------------------------------------
__global__ __launch_bounds__(256) void k_fit4(
    const float* __restrict__ D, const bf16x8* __restrict__ fragsF,
    const bf16x8* __restrict__ fragsG1, const bf16x8* __restrict__ fragsG2,
    const float* __restrict__ bf0, const float* __restrict__ bf1,
    const float* __restrict__ bf2,
    const float* __restrict__ Wf3, const float* __restrict__ bf3,
    float* __restrict__ Q)
{
    __shared__ float HT0[64 * HP];   // 16.25 KB, [feat][row]
    __shared__ float HT1[64 * HP];   // 16.25 KB, [feat][row]
    __shared__ float Qp[64];

    const int tid  = threadIdx.x;
    const int wv   = tid >> 6;
    const int l    = tid & 63;
    const int row0 = l & 15;
    const int grp  = l >> 4;

    // ---------------- layer 0 (MFMA): D[256] -> 64, tanh ----------------
    {
        const float* __restrict__ drow =
            D + (size_t)(blockIdx.x * 64 + wv * 16 + row0) * 256;

        vf4 c[4];
#pragma unroll
        for (int nt = 0; nt < 4; ++nt) c[nt] = bf0[nt * 16 + row0];

#pragma unroll
        for (int k = 0; k < 8; ++k) {
            vf4 x0 = ld4(drow + k * 32 + grp * 8);
            vf4 x1 = ld4(drow + k * 32 + grp * 8 + 4);
            bf16x8 ah, al;
            split8v(x0, x1, ah, al);
#pragma unroll
            for (int nt = 0; nt < 4; ++nt) {
                const int combo = k * 4 + nt;
                c[nt] = mm3(ah, al, fragsF[(combo * 2 + 0) * 64 + l],
                                    fragsF[(combo * 2 + 1) * 64 + l], c[nt]);
            }
        }
#pragma unroll
        for (int nt = 0; nt < 4; ++nt)
#pragma unroll
            for (int e = 0; e < 4; ++e)
                HT0[(nt * 16 + row0) * HP + wv * 16 + grp * 4 + e] = ftanh(c[nt][e]);
    }

    // ---------------- layer 1 (MFMA): 64 -> 64, sigmoid ----------------
    {
        vf4 c[4];
#pragma unroll
        for (int nt = 0; nt < 4; ++nt) c[nt] = bf1[nt * 16 + row0];
#pragma unroll
        for (int ktile = 0; ktile < 2; ++ktile) {
            vf4 x0, x1;
#pragma unroll
            for (int e = 0; e < 4; ++e) {
                x0[e] = HT0[(ktile * 32 + grp * 8 + e) * HP + wv * 16 + row0];
                x1[e] = HT0[(ktile * 32 + grp * 8 + 4 + e) * HP + wv * 16 + row0];
            }
            bf16x8 ah, al;
            split8v(x0, x1, ah, al);
#pragma unroll
            for (int nt = 0; nt < 4; ++nt) {
                const int combo = ktile * 4 + nt;
                c[nt] = mm3(ah, al, fragsG1[(combo * 2 + 0) * 64 + l],
                                    fragsG1[(combo * 2 + 1) * 64 + l], c[nt]);
            }
        }
#pragma unroll
        for (int nt = 0; nt < 4; ++nt)
#pragma unroll
            for (int e = 0; e < 4; ++e)
                HT1[(nt * 16 + row0) * HP + wv * 16 + grp * 4 + e] = fsig(c[nt][e]);
    }

    // ---------------- layer 2 (MFMA): 64 -> 64 (tanh in L3) -------------
    vf4 c2[4];
    {
#pragma unroll
        for (int nt = 0; nt < 4; ++nt) c2[nt] = bf2[nt * 16 + row0];
#pragma unroll
        for (int ktile = 0; ktile < 2; ++ktile) {
            vf4 x0, x1;
#pragma unroll
            for (int e = 0; e < 4; ++e) {
                x0[e] = HT1[(ktile * 32 + grp * 8 + e) * HP + wv * 16 + row0];
                x1[e] = HT1[(ktile * 32 + grp * 8 + 4 + e) * HP + wv * 16 + row0];
            }
            bf16x8 ah, al;
            split8v(x0, x1, ah, al);
#pragma unroll
            for (int nt = 0; nt < 4; ++nt) {
                const int combo = ktile * 4 + nt;
                c2[nt] = mm3(ah, al, fragsG2[(combo * 2 + 0) * 64 + l],
                                     fragsG2[(combo * 2 + 1) * 64 + l], c2[nt]);
            }
        }
    }

    // ---------------- layer 3: tanh + dot with Wf3, reduce over row0 ----
    {
        float p[4] = {0.f, 0.f, 0.f, 0.f};   // rows wv*16 + grp*4 + e
#pragma unroll
        for (int nt = 0; nt < 4; ++nt) {
            const float w3 = Wf3[nt * 16 + row0];
#pragma unroll
            for (int e = 0; e < 4; ++e) p[e] += ftanh(c2[nt][e]) * w3;
        }
#pragma unroll
        for (int e = 0; e < 4; ++e) {
            float v = p[e];
            v += __shfl_xor(v, 1);
            v += __shfl_xor(v, 2);
            v += __shfl_xor(v, 4);
            v += __shfl_xor(v, 8);
            if (row0 == 0) Qp[wv * 16 + grp * 4 + e] = v;
        }
    }
    __syncthreads();

    if (tid < 64)
        Q[(size_t)blockIdx.x * 64 + tid] = bf3[0] + Qp[tid];
}

// ---------------------------------------------------------------------------
// K3: deterministic mean over N per batch element.
// ---------------------------------------------------------------------------
__global__ __launch_bounds__(256) void k_mean(const float* __restrict__ Q,
                                              float* __restrict__ out)
{
    __shared__ float s[256];
    const int b = blockIdx.x;
    const int t = threadIdx.x;
    float v = Q[b * NN + t] + Q[b * NN + 256 + t];
    s[t] = v;
    __syncthreads();
#pragma unroll
    for (int off = 128; off > 0; off >>= 1) {
        if (t < off) s[t] += s[t + off];
        __syncthreads();
    }
    if (t == 0) out[b] = s[0] * (1.0f / (float)NN);
}

// ---------------------------------------------------------------------------
extern "C" void kernel_launch(void* const* d_in, const int* in_sizes, int n_in,
                              void* d_out, int out_size, void* d_ws, size_t ws_size,
                              hipStream_t stream)
{
    const float* Sg  = (const float*)d_in[0];
    const float* R   = (const float*)d_in[1];
    const float* We0 = (const float*)d_in[2];
    const float* be0 = (const float*)d_in[3];
    const float* We1 = (const float*)d_in[4];
    const float* be1 = (const float*)d_in[5];
    const float* We2 = (const float*)d_in[6];
    const float* be2 = (const float*)d_in[7];
    const float* Wf0 = (const float*)d_in[8];
    const float* bf0 = (const float*)d_in[9];
    const float* Wf1 = (const float*)d_in[10];
    const float* bf1 = (const float*)d_in[11];
    const float* Wf2 = (const float*)d_in[12];
    const float* bf2 = (const float*)d_in[13];
    const float* Wf3 = (const float*)d_in[14];
    const float* bf3 = (const float*)d_in[15];

    char* ws = (char*)d_ws;
    float*  Dm      = (float*)ws;                                  // 33.55 MB
    float*  Q       = (float*)(ws + (size_t)BN_TOTAL * 256 * 4);   // 128 KB
    char*   tb      = ws + (size_t)BN_TOTAL * 256 * 4 + (size_t)BN_TOTAL * 4;
    bf16x8* fragsE  = (bf16x8*)tb;               // 8 KB
    bf16x8* fragsF  = (bf16x8*)(tb + 8192);      // 64 KB
    bf16x8* fragsG1 = (bf16x8*)(tb + 8192 + 65536);          // 16 KB
    bf16x8* fragsG2 = (bf16x8*)(tb + 8192 + 65536 + 16384);  // 16 KB

    k_prep<<<13, 256, 0, stream>>>(We1, We2, Wf0, Wf1, Wf2,
                                   fragsE, fragsF, fragsG1, fragsG2);
    k_emb_mfma<<<BN_TOTAL / 2, 128, 0, stream>>>(Sg, R, We0, be0, be1, be2, fragsE, Dm);
    k_fit4<<<BN_TOTAL / 64, 256, 0, stream>>>(Dm, fragsF, fragsG1, fragsG2,
                                              bf0, bf1, bf2, Wf3, bf3, Q);
    k_mean<<<BB, 256, 0, stream>>>(Q, (float*)d_out);
}